// Round 1
// baseline (1889.837 us; speedup 1.0000x reference)
//
#include <hip/hip_runtime.h>
#include <stdint.h>

// ---------- types / helpers ----------
typedef __bf16 bf16x8 __attribute__((ext_vector_type(8)));
typedef float  f32x4  __attribute__((ext_vector_type(4)));

__device__ __forceinline__ uint16_t f2b(float f) {
  uint32_t u = __float_as_uint(f);
  u += 0x7fffu + ((u >> 16) & 1u);        // round-to-nearest-even
  return (uint16_t)(u >> 16);
}
__device__ __forceinline__ float b2f(uint16_t h) {
  return __uint_as_float(((uint32_t)h) << 16);
}

#define MFMA16(a,b,c) __builtin_amdgcn_mfma_f32_16x16x32_bf16((a),(b),(c),0,0,0)

// ---------- constants (problem shape, baked) ----------
// B=2 S=2048 DIM=2048 HEADS=16 HD=128 FF=8192 PREV=1024 T=3072

// ---------- rmsnorm (f32 in -> bf16 out), row length 2048 ----------
__global__ __launch_bounds__(256)
void rmsnorm_k(const float* __restrict__ x, const float* __restrict__ w,
               uint16_t* __restrict__ out) {
  __shared__ float red[4];
  const int row = blockIdx.x, tid = threadIdx.x;
  const float* xr = x + (size_t)row * 2048;
  const int c = tid * 8;
  float4 a = *(const float4*)&xr[c];
  float4 b = *(const float4*)&xr[c + 4];
  float ss = a.x*a.x + a.y*a.y + a.z*a.z + a.w*a.w
           + b.x*b.x + b.y*b.y + b.z*b.z + b.w*b.w;
  ss += __shfl_xor(ss, 1);  ss += __shfl_xor(ss, 2);  ss += __shfl_xor(ss, 4);
  ss += __shfl_xor(ss, 8);  ss += __shfl_xor(ss, 16); ss += __shfl_xor(ss, 32);
  if ((tid & 63) == 0) red[tid >> 6] = ss;
  __syncthreads();
  const float tot = red[0] + red[1] + red[2] + red[3];
  const float rms = rsqrtf(tot * (1.0f / 2048.0f) + 1e-6f);
  float4 w0 = *(const float4*)&w[c];
  float4 w1 = *(const float4*)&w[c + 4];
  uint16_t* orow = out + (size_t)row * 2048;
  orow[c+0] = f2b(a.x * rms * w0.x); orow[c+1] = f2b(a.y * rms * w0.y);
  orow[c+2] = f2b(a.z * rms * w0.z); orow[c+3] = f2b(a.w * rms * w0.w);
  orow[c+4] = f2b(b.x * rms * w1.x); orow[c+5] = f2b(b.y * rms * w1.y);
  orow[c+6] = f2b(b.z * rms * w1.z); orow[c+7] = f2b(b.w * rms * w1.w);
}

// ---------- bias concat: [bq|bk|bv] -> 6144 f32 ----------
__global__ void biascat_k(const float* __restrict__ bq, const float* __restrict__ bk,
                          const float* __restrict__ bv, float* __restrict__ out) {
  int i = blockIdx.x * 256 + threadIdx.x;
  if (i < 6144)
    out[i] = (i < 2048) ? bq[i] : ((i < 4096) ? bk[i - 2048] : bv[i - 4096]);
}

// ---------- transpose-convert: src (K,N) f32 -> dst (N,K) bf16 ----------
__global__ __launch_bounds__(256)
void transpose_k(const float* __restrict__ src, uint16_t* __restrict__ dst,
                 int K, int N) {
  __shared__ float tile[32][33];
  const int tx = threadIdx.x & 31, ty = threadIdx.x >> 5;   // 32 x 8
  const int n0 = blockIdx.x * 32, k0 = blockIdx.y * 32;
  #pragma unroll
  for (int i = 0; i < 4; ++i)
    tile[ty + i*8][tx] = src[(size_t)(k0 + ty + i*8) * N + n0 + tx];
  __syncthreads();
  #pragma unroll
  for (int i = 0; i < 4; ++i)
    dst[(size_t)(n0 + ty + i*8) * K + k0 + tx] = f2b(tile[tx][ty + i*8]);
}

// ---------- KV-cache copy: (BH,1024,128) f32 -> (BH,3072,128) f32 [:1024] ----------
__global__ __launch_bounds__(256)
void copy_cache_k(const float4* __restrict__ src, float4* __restrict__ dst) {
  const int idx = blockIdx.x * 256 + threadIdx.x;      // 1,048,576 total
  const int c4 = idx & 31, t = (idx >> 5) & 1023, bh = idx >> 15;
  dst[((size_t)bh * 3072 + t) * 32 + c4] = src[idx];
}

// ---------- RoPE + scatter: qkv (B*S,6144) bf16 -> q_b bf16 (B,H,S,128),
//            k/v -> f32 outputs at t = 1024+s ----------
__global__ __launch_bounds__(256)
void rope_k(const uint16_t* __restrict__ qkv, const float* __restrict__ fc,
            const float* __restrict__ fs, uint16_t* __restrict__ qb,
            float* __restrict__ kat, float* __restrict__ vat) {
  const int bi = blockIdx.x;                // B*S*4 = 16384 blocks
  const int bs = bi >> 2;                   // b*2048 + s
  const int h  = ((bi & 3) << 2) + (threadIdx.x >> 6);
  const int d  = threadIdx.x & 63;
  const int b  = bs >> 11, s = bs & 2047;
  const int pos = s + 1024;                 // start_pos = PREV = 1024, no wrap
  const float c  = fc[pos * 64 + d];
  const float sn = fs[pos * 64 + d];
  const uint16_t* row = qkv + (size_t)bs * 6144 + h * 128;
  const float q0 = b2f(row[2*d]),        q1 = b2f(row[2*d + 1]);
  const float k0 = b2f(row[2048 + 2*d]), k1 = b2f(row[2048 + 2*d + 1]);
  const float v0 = b2f(row[4096 + 2*d]), v1 = b2f(row[4096 + 2*d + 1]);
  const size_t qo = (((size_t)b*16 + h) * 2048 + s) * 128 + 2*d;
  qb[qo]     = f2b(q0 * c - q1 * sn);
  qb[qo + 1] = f2b(q0 * sn + q1 * c);
  const size_t ko = (((size_t)b*16 + h) * 3072 + 1024 + s) * 128 + 2*d;
  kat[ko]     = k0 * c - k1 * sn;
  kat[ko + 1] = k0 * sn + k1 * c;
  vat[ko]     = v0;
  vat[ko + 1] = v1;
}

// ---------- flash attention: blocks = BH*32 (64 q-rows each), 4 waves x 16 rows ----------
__global__ __launch_bounds__(256)
void attn_k(const uint16_t* __restrict__ qb, const float* __restrict__ kat,
            const float* __restrict__ vat, uint16_t* __restrict__ ob) {
  __shared__ uint16_t lsK[32 * 136];        // [key][dh] natural, pad 8
  __shared__ uint16_t lsV[128 * 40];        // [dh][key] transposed, pad 8
  __shared__ uint16_t lsP[4][16 * 40];      // per-wave P, pad 8
  const int tid = threadIdx.x;
  const int lane = tid & 63, w = tid >> 6;
  const int l15 = lane & 15, q4 = lane >> 4;
  const int bh = blockIdx.x >> 5;           // b*16+h
  const int q0 = (blockIdx.x & 31) * 64;
  const int s_w = q0 + w * 16;              // this wave's first q row

  // Q fragments (A-operand): m=l15 (row), k=kc*32+q4*8+j
  bf16x8 qf[4];
  const uint16_t* qrow = qb + ((size_t)bh * 2048 + s_w + l15) * 128;
  #pragma unroll
  for (int kc = 0; kc < 4; ++kc)
    qf[kc] = *(const bf16x8*)&qrow[kc * 32 + q4 * 8];

  f32x4 o[8];
  #pragma unroll
  for (int nt = 0; nt < 8; ++nt) o[nt] = (f32x4){0.f, 0.f, 0.f, 0.f};
  float mrow[4], lrow[4];
  #pragma unroll
  for (int r = 0; r < 4; ++r) { mrow[r] = -1e30f; lrow[r] = 0.f; }

  const float SC = 0.08838834764831845f * 1.4426950408889634f; // /sqrt(128) * log2(e)
  const int ntiles = (q0 + 1088) >> 5;
  const float* kbase = kat + (size_t)bh * 3072 * 128;
  const float* vbase = vat + (size_t)bh * 3072 * 128;

  for (int tt = 0; tt < ntiles; ++tt) {
    const int t0 = tt << 5;
    __syncthreads();                         // previous tile fully consumed
    #pragma unroll
    for (int p = 0; p < 4; ++p) {            // stage 32 keys x 128 dh, f32->bf16
      const int idx = tid + p * 256;
      const int key = idx >> 5, c4 = (idx & 31) << 2;
      float4 kv = *(const float4*)&kbase[(size_t)(t0 + key) * 128 + c4];
      float4 vv = *(const float4*)&vbase[(size_t)(t0 + key) * 128 + c4];
      uint2 kp;
      kp.x = (uint32_t)f2b(kv.x) | ((uint32_t)f2b(kv.y) << 16);
      kp.y = (uint32_t)f2b(kv.z) | ((uint32_t)f2b(kv.w) << 16);
      *(uint2*)&lsK[key * 136 + c4] = kp;
      lsV[(c4 + 0) * 40 + key] = f2b(vv.x);
      lsV[(c4 + 1) * 40 + key] = f2b(vv.y);
      lsV[(c4 + 2) * 40 + key] = f2b(vv.z);
      lsV[(c4 + 3) * 40 + key] = f2b(vv.w);
    }
    __syncthreads();
    // S = Q K^T : two 16-key n-tiles, 4 k-chunks
    f32x4 s0 = (f32x4){0.f,0.f,0.f,0.f}, s1 = (f32x4){0.f,0.f,0.f,0.f};
    #pragma unroll
    for (int kc = 0; kc < 4; ++kc) {
      bf16x8 kf0 = *(const bf16x8*)&lsK[(l15)      * 136 + kc * 32 + q4 * 8];
      bf16x8 kf1 = *(const bf16x8*)&lsK[(16 + l15) * 136 + kc * 32 + q4 * 8];
      s0 = MFMA16(qf[kc], kf0, s0);
      s1 = MFMA16(qf[kc], kf1, s1);
    }
    // scale + causal mask (allowed: t <= 1024 + s)
    float sc0[4], sc1[4];
    #pragma unroll
    for (int r = 0; r < 4; ++r) {
      const int lim = 1024 + s_w + q4 * 4 + r;
      sc0[r] = (t0 + l15      <= lim) ? s0[r] * SC : -1e30f;
      sc1[r] = (t0 + 16 + l15 <= lim) ? s1[r] * SC : -1e30f;
    }
    // online softmax: row max across quad's 16 lanes
    float alpha[4];
    #pragma unroll
    for (int r = 0; r < 4; ++r) {
      float v = fmaxf(sc0[r], sc1[r]);
      v = fmaxf(v, __shfl_xor(v, 1)); v = fmaxf(v, __shfl_xor(v, 2));
      v = fmaxf(v, __shfl_xor(v, 4)); v = fmaxf(v, __shfl_xor(v, 8));
      const float mn = fmaxf(mrow[r], v);
      alpha[r] = exp2f(mrow[r] - mn);
      mrow[r] = mn;
    }
    // P = exp2(sc - m), row sums, write P (bf16) to per-wave LDS
    #pragma unroll
    for (int r = 0; r < 4; ++r) {
      const float p0 = exp2f(sc0[r] - mrow[r]);
      const float p1 = exp2f(sc1[r] - mrow[r]);
      float ps = p0 + p1;
      ps += __shfl_xor(ps, 1); ps += __shfl_xor(ps, 2);
      ps += __shfl_xor(ps, 4); ps += __shfl_xor(ps, 8);
      lrow[r] = lrow[r] * alpha[r] + ps;
      lsP[w][(q4 * 4 + r) * 40 + l15]      = f2b(p0);
      lsP[w][(q4 * 4 + r) * 40 + 16 + l15] = f2b(p1);
    }
    // rescale O, then O += P V   (per-wave LDS: same-wave DS ordering is in-order)
    #pragma unroll
    for (int nt = 0; nt < 8; ++nt)
      #pragma unroll
      for (int r = 0; r < 4; ++r) o[nt][r] *= alpha[r];
    bf16x8 pf = *(const bf16x8*)&lsP[w][l15 * 40 + q4 * 8];
    #pragma unroll
    for (int nt = 0; nt < 8; ++nt) {
      bf16x8 vf = *(const bf16x8*)&lsV[(nt * 16 + l15) * 40 + q4 * 8];
      o[nt] = MFMA16(pf, vf, o[nt]);
    }
  }
  // write O/l to (B,S,D) bf16
  const int b = bh >> 4, h = bh & 15;
  #pragma unroll
  for (int r = 0; r < 4; ++r) {
    const float inv = 1.0f / lrow[r];
    const int s = s_w + q4 * 4 + r;
    uint16_t* orow = ob + ((size_t)b * 2048 + s) * 2048 + h * 128;
    #pragma unroll
    for (int nt = 0; nt < 8; ++nt)
      orow[nt * 16 + l15] = f2b(o[nt][r] * inv);
  }
}

// ---------- GEMM: C = A(MxK bf16) * Bt(NxK bf16)^T + bias, 128x128 tile, BK=32 ----------
// EPI 0: out bf16 = acc+bias
// EPI 1: out f32  = acc+bias+resid
// EPI 2: out bf16 = silu(g)* (acc+bias), g read from gbuf (bf16)
template <int EPI>
__global__ __launch_bounds__(256)
void gemm_k(const uint16_t* __restrict__ A, const uint16_t* __restrict__ Bt,
            const float* __restrict__ bias, const float* __restrict__ resid,
            const uint16_t* __restrict__ gbuf, void* __restrict__ outp,
            int M, int N, int K) {
  __shared__ uint16_t lsA[128 * 40];
  __shared__ uint16_t lsB[128 * 40];
  const int tid = threadIdx.x;
  const int lane = tid & 63, wvi = tid >> 6;
  const int l15 = lane & 15, q4 = lane >> 4;
  const int wm = wvi & 1, wn = wvi >> 1;
  const int m0 = blockIdx.y * 128, n0 = blockIdx.x * 128;

  f32x4 acc[4][4];
  #pragma unroll
  for (int i = 0; i < 4; ++i)
    #pragma unroll
    for (int j = 0; j < 4; ++j) acc[i][j] = (f32x4){0.f, 0.f, 0.f, 0.f};

  const int nkt = K >> 5;
  for (int kt = 0; kt < nkt; ++kt) {
    const int k0 = kt << 5;
    #pragma unroll
    for (int p = 0; p < 2; ++p) {
      const int idx = tid + p * 256;
      const int row = idx >> 2, c8 = (idx & 3) << 3;
      *(uint4*)&lsA[row * 40 + c8] = *(const uint4*)&A[(size_t)(m0 + row) * K + k0 + c8];
      *(uint4*)&lsB[row * 40 + c8] = *(const uint4*)&Bt[(size_t)(n0 + row) * K + k0 + c8];
    }
    __syncthreads();
    bf16x8 af[4], bfr[4];
    #pragma unroll
    for (int i = 0; i < 4; ++i)
      af[i] = *(const bf16x8*)&lsA[(wm * 64 + i * 16 + l15) * 40 + q4 * 8];
    #pragma unroll
    for (int j = 0; j < 4; ++j)
      bfr[j] = *(const bf16x8*)&lsB[(wn * 64 + j * 16 + l15) * 40 + q4 * 8];
    #pragma unroll
    for (int i = 0; i < 4; ++i)
      #pragma unroll
      for (int j = 0; j < 4; ++j)
        acc[i][j] = MFMA16(af[i], bfr[j], acc[i][j]);
    __syncthreads();
  }
  // epilogue: row m = m0+wm*64+i*16+q4*4+r, col n = n0+wn*64+j*16+l15
  #pragma unroll
  for (int i = 0; i < 4; ++i) {
    #pragma unroll
    for (int j = 0; j < 4; ++j) {
      const int n = n0 + wn * 64 + j * 16 + l15;
      const float bn = bias[n];
      #pragma unroll
      for (int r = 0; r < 4; ++r) {
        const int m = m0 + wm * 64 + i * 16 + q4 * 4 + r;
        const size_t off = (size_t)m * N + n;
        const float v = acc[i][j][r] + bn;
        if (EPI == 0) {
          ((uint16_t*)outp)[off] = f2b(v);
        } else if (EPI == 1) {
          ((float*)outp)[off] = v + resid[off];
        } else {
          const float g = b2f(gbuf[off]);
          const float sg = g / (1.0f + __expf(-g));
          ((uint16_t*)outp)[off] = f2b(sg * v);
        }
      }
    }
  }
}

// ---------- launch ----------
extern "C" void kernel_launch(void* const* d_in, const int* in_sizes, int n_in,
                              void* d_out, int out_size, void* d_ws, size_t ws_size,
                              hipStream_t stream) {
  const float* x   = (const float*)d_in[0];
  const float* kc  = (const float*)d_in[1];
  const float* vc  = (const float*)d_in[2];
  const float* anw = (const float*)d_in[3];
  const float* fnw = (const float*)d_in[4];
  const float* wq  = (const float*)d_in[5];
  const float* bq  = (const float*)d_in[6];
  const float* wk  = (const float*)d_in[7];
  const float* bk  = (const float*)d_in[8];
  const float* wv_ = (const float*)d_in[9];
  const float* bv  = (const float*)d_in[10];
  const float* wo  = (const float*)d_in[11];
  const float* bo  = (const float*)d_in[12];
  const float* wg  = (const float*)d_in[13];
  const float* bg  = (const float*)d_in[14];
  const float* wva = (const float*)d_in[15];
  const float* bva = (const float*)d_in[16];
  const float* wp  = (const float*)d_in[17];
  const float* bp  = (const float*)d_in[18];
  const float* fc  = (const float*)d_in[19];
  const float* fs  = (const float*)d_in[20];

  float* out_x = (float*)d_out;               // (2,2048,2048)
  float* kat = out_x + 8388608;               // (2,16,3072,128)
  float* vat = kat + 12582912;

  char* ws = (char*)d_ws;
  uint16_t* h_b   = (uint16_t*)(ws);                       // 16 MB  (h / h2 bf16)
  uint16_t* wbuf  = (uint16_t*)(ws + 16777216);            // 32 MB  (transposed bf16 weights, reused)
  uint16_t* qkv_b = (uint16_t*)(ws + 50331648);            // 48 MB  (qkv bf16)
  uint16_t* q_b   = (uint16_t*)(ws + 100663296);           // 16 MB  (roped Q, (B,H,S,128))
  uint16_t* o_b   = (uint16_t*)(ws + 117440512);           // 16 MB  (attn out, (B,S,D))
  float*    x1    = (float*)   (ws + 134217728);           // 32 MB  (post-attn residual f32)
  float*    bcat  = (float*)   (ws + 167772160);           // 24 KB  (qkv bias concat)
  uint16_t* g_b   = qkv_b;                                 // 64 MB overlay (gate/ff bf16)

  // attention block
  rmsnorm_k<<<4096, 256, 0, stream>>>(x, anw, h_b);
  biascat_k<<<24, 256, 0, stream>>>(bq, bk, bv, bcat);
  transpose_k<<<dim3(64, 64), 256, 0, stream>>>(wq,  wbuf,                 2048, 2048);
  transpose_k<<<dim3(64, 64), 256, 0, stream>>>(wk,  wbuf + 1*2048*2048,   2048, 2048);
  transpose_k<<<dim3(64, 64), 256, 0, stream>>>(wv_, wbuf + 2*2048*2048,   2048, 2048);
  gemm_k<0><<<dim3(48, 32), 256, 0, stream>>>(h_b, wbuf, bcat, nullptr, nullptr,
                                              (void*)qkv_b, 4096, 6144, 2048);
  copy_cache_k<<<4096, 256, 0, stream>>>((const float4*)kc, (float4*)kat);
  copy_cache_k<<<4096, 256, 0, stream>>>((const float4*)vc, (float4*)vat);
  rope_k<<<16384, 256, 0, stream>>>(qkv_b, fc, fs, q_b, kat, vat);
  attn_k<<<1024, 256, 0, stream>>>(q_b, kat, vat, o_b);
  transpose_k<<<dim3(64, 64), 256, 0, stream>>>(wo, wbuf, 2048, 2048);
  gemm_k<1><<<dim3(16, 32), 256, 0, stream>>>(o_b, wbuf, bo, x, nullptr,
                                              (void*)x1, 4096, 2048, 2048);
  // FFN block
  rmsnorm_k<<<4096, 256, 0, stream>>>(x1, fnw, h_b);
  transpose_k<<<dim3(256, 64), 256, 0, stream>>>(wg, wbuf, 2048, 8192);
  gemm_k<0><<<dim3(64, 32), 256, 0, stream>>>(h_b, wbuf, bg, nullptr, nullptr,
                                              (void*)g_b, 4096, 8192, 2048);
  transpose_k<<<dim3(256, 64), 256, 0, stream>>>(wva, wbuf, 2048, 8192);
  gemm_k<2><<<dim3(64, 32), 256, 0, stream>>>(h_b, wbuf, bva, nullptr, g_b,
                                              (void*)g_b, 4096, 8192, 2048);
  transpose_k<<<dim3(64, 256), 256, 0, stream>>>(wp, wbuf, 8192, 2048);
  gemm_k<1><<<dim3(16, 32), 256, 0, stream>>>(g_b, wbuf, bp, x1, nullptr,
                                              (void*)out_x, 4096, 2048, 8192);
}

// Round 2
// 1474.743 us; speedup vs baseline: 1.2815x; 1.2815x over previous
//
#include <hip/hip_runtime.h>
#include <stdint.h>

// ---------- types / helpers ----------
typedef __bf16 bf16x8 __attribute__((ext_vector_type(8)));
typedef float  f32x4  __attribute__((ext_vector_type(4)));

__device__ __forceinline__ uint16_t f2b(float f) {
  uint32_t u = __float_as_uint(f);
  u += 0x7fffu + ((u >> 16) & 1u);        // round-to-nearest-even
  return (uint16_t)(u >> 16);
}
__device__ __forceinline__ float b2f(uint16_t h) {
  return __uint_as_float(((uint32_t)h) << 16);
}

// async global->LDS, 16B per lane; LDS dst = wave-uniform base + lane*16
__device__ __forceinline__ void gl_lds16(const uint16_t* g, uint16_t* l) {
  __builtin_amdgcn_global_load_lds(
      (const __attribute__((address_space(1))) uint32_t*)g,
      (__attribute__((address_space(3))) uint32_t*)l, 16, 0, 0);
}

#define MFMA16(a,b,c) __builtin_amdgcn_mfma_f32_16x16x32_bf16((a),(b),(c),0,0,0)

// B=2 S=2048 DIM=2048 HEADS=16 HD=128 FF=8192 PREV=1024 T=3072

// ---------- rmsnorm (f32 in -> bf16 out), row length 2048 ----------
__global__ __launch_bounds__(256)
void rmsnorm_k(const float* __restrict__ x, const float* __restrict__ w,
               uint16_t* __restrict__ out) {
  __shared__ float red[4];
  const int row = blockIdx.x, tid = threadIdx.x;
  const float* xr = x + (size_t)row * 2048;
  const int c = tid * 8;
  float4 a = *(const float4*)&xr[c];
  float4 b = *(const float4*)&xr[c + 4];
  float ss = a.x*a.x + a.y*a.y + a.z*a.z + a.w*a.w
           + b.x*b.x + b.y*b.y + b.z*b.z + b.w*b.w;
  ss += __shfl_xor(ss, 1);  ss += __shfl_xor(ss, 2);  ss += __shfl_xor(ss, 4);
  ss += __shfl_xor(ss, 8);  ss += __shfl_xor(ss, 16); ss += __shfl_xor(ss, 32);
  if ((tid & 63) == 0) red[tid >> 6] = ss;
  __syncthreads();
  const float tot = red[0] + red[1] + red[2] + red[3];
  const float rms = rsqrtf(tot * (1.0f / 2048.0f) + 1e-6f);
  float4 w0 = *(const float4*)&w[c];
  float4 w1 = *(const float4*)&w[c + 4];
  uint16_t* orow = out + (size_t)row * 2048;
  orow[c+0] = f2b(a.x * rms * w0.x); orow[c+1] = f2b(a.y * rms * w0.y);
  orow[c+2] = f2b(a.z * rms * w0.z); orow[c+3] = f2b(a.w * rms * w0.w);
  orow[c+4] = f2b(b.x * rms * w1.x); orow[c+5] = f2b(b.y * rms * w1.y);
  orow[c+6] = f2b(b.z * rms * w1.z); orow[c+7] = f2b(b.w * rms * w1.w);
}

// ---------- bias concat: [bq|bk|bv] -> 6144 f32 ----------
__global__ void biascat_k(const float* __restrict__ bq, const float* __restrict__ bk,
                          const float* __restrict__ bv, float* __restrict__ out) {
  int i = blockIdx.x * 256 + threadIdx.x;
  if (i < 6144)
    out[i] = (i < 2048) ? bq[i] : ((i < 4096) ? bk[i - 2048] : bv[i - 4096]);
}

// ---------- transpose-convert: src (K,N) f32 -> dst (N,K) bf16 ----------
__global__ __launch_bounds__(256)
void transpose_k(const float* __restrict__ src, uint16_t* __restrict__ dst,
                 int K, int N) {
  __shared__ float tile[32][33];
  const int tx = threadIdx.x & 31, ty = threadIdx.x >> 5;   // 32 x 8
  const int n0 = blockIdx.x * 32, k0 = blockIdx.y * 32;
  #pragma unroll
  for (int i = 0; i < 4; ++i)
    tile[ty + i*8][tx] = src[(size_t)(k0 + ty + i*8) * N + n0 + tx];
  __syncthreads();
  #pragma unroll
  for (int i = 0; i < 4; ++i)
    dst[(size_t)(n0 + ty + i*8) * K + k0 + tx] = f2b(tile[tx][ty + i*8]);
}

// ---------- batched V transpose: (32,3072,128) f32 -> (32,128,3072) bf16 ----------
__global__ __launch_bounds__(256)
void transpose_v_k(const float* __restrict__ src, uint16_t* __restrict__ dst) {
  __shared__ float tile[32][33];
  const int tx = threadIdx.x & 31, ty = threadIdx.x >> 5;
  const int t0 = blockIdx.x * 32, d0 = blockIdx.y * 32, bh = blockIdx.z;
  const float* s = src + (size_t)bh * 393216;
  uint16_t*   d = dst + (size_t)bh * 393216;
  #pragma unroll
  for (int i = 0; i < 4; ++i)
    tile[ty + i*8][tx] = s[(size_t)(t0 + ty + i*8) * 128 + d0 + tx];
  __syncthreads();
  #pragma unroll
  for (int i = 0; i < 4; ++i)
    d[(size_t)(d0 + ty + i*8) * 3072 + t0 + tx] = f2b(tile[tx][ty + i*8]);
}

// ---------- f32 -> bf16 convert (8 el/thread) ----------
__global__ __launch_bounds__(256)
void cvt_bf16_k(const float* __restrict__ src, uint16_t* __restrict__ dst) {
  const int i = blockIdx.x * 256 + threadIdx.x;
  float4 a = ((const float4*)src)[2*i];
  float4 b = ((const float4*)src)[2*i + 1];
  ushort4 lo, hi;
  lo.x = f2b(a.x); lo.y = f2b(a.y); lo.z = f2b(a.z); lo.w = f2b(a.w);
  hi.x = f2b(b.x); hi.y = f2b(b.y); hi.z = f2b(b.z); hi.w = f2b(b.w);
  ((ushort4*)dst)[2*i] = lo;
  ((ushort4*)dst)[2*i + 1] = hi;
}

// ---------- KV-cache copy: (BH,1024,128) f32 -> (BH,3072,128) f32 [:1024] ----------
__global__ __launch_bounds__(256)
void copy_cache_k(const float4* __restrict__ src, float4* __restrict__ dst) {
  const int idx = blockIdx.x * 256 + threadIdx.x;      // 1,048,576 total
  const int c4 = idx & 31, t = (idx >> 5) & 1023, bh = idx >> 15;
  dst[((size_t)bh * 3072 + t) * 32 + c4] = src[idx];
}

// ---------- RoPE + scatter ----------
__global__ __launch_bounds__(256)
void rope_k(const uint16_t* __restrict__ qkv, const float* __restrict__ fc,
            const float* __restrict__ fs, uint16_t* __restrict__ qb,
            float* __restrict__ kat, float* __restrict__ vat) {
  const int bi = blockIdx.x;                // B*S*4 = 16384 blocks
  const int bs = bi >> 2;                   // b*2048 + s
  const int h  = ((bi & 3) << 2) + (threadIdx.x >> 6);
  const int d  = threadIdx.x & 63;
  const int b  = bs >> 11, s = bs & 2047;
  const int pos = s + 1024;
  const float c  = fc[pos * 64 + d];
  const float sn = fs[pos * 64 + d];
  const uint16_t* row = qkv + (size_t)bs * 6144 + h * 128;
  const float q0 = b2f(row[2*d]),        q1 = b2f(row[2*d + 1]);
  const float k0 = b2f(row[2048 + 2*d]), k1 = b2f(row[2048 + 2*d + 1]);
  const float v0 = b2f(row[4096 + 2*d]), v1 = b2f(row[4096 + 2*d + 1]);
  const size_t qo = (((size_t)b*16 + h) * 2048 + s) * 128 + 2*d;
  qb[qo]     = f2b(q0 * c - q1 * sn);
  qb[qo + 1] = f2b(q0 * sn + q1 * c);
  const size_t ko = (((size_t)b*16 + h) * 3072 + 1024 + s) * 128 + 2*d;
  kat[ko]     = k0 * c - k1 * sn;
  kat[ko + 1] = k0 * sn + k1 * c;
  vat[ko]     = v0;
  vat[ko + 1] = v1;
}

// ---------- flash attention v2: async bf16 staging, swizzled K, pre-transposed V ----------
__global__ __launch_bounds__(256)
void attn_k(const uint16_t* __restrict__ qb, const uint16_t* __restrict__ kb,
            const uint16_t* __restrict__ vt, uint16_t* __restrict__ ob) {
  __shared__ __align__(16) uint16_t lsK[32 * 128];  // [key][chunk^(key&15)] swizzled
  __shared__ __align__(16) uint16_t lsV[128 * 32];  // [d][t] pre-transposed, ld=32
  __shared__ __align__(16) uint16_t lsP[4][16 * 40];
  const int tid = threadIdx.x;
  const int lane = tid & 63, w = tid >> 6;
  const int l15 = lane & 15, q4 = lane >> 4;
  const int bh = blockIdx.x & 31;                   // b*16+h
  const int qi = 31 - (blockIdx.x >> 5);            // largest-work blocks first
  const int q0 = qi * 64;
  const int s_w = q0 + w * 16;

  // staging source offsets (element units)
  int koff[2], voff[2];
  #pragma unroll
  for (int p = 0; p < 2; ++p) {
    const int idk = p * 256 + tid;
    const int krow = idk >> 4, kchp = idk & 15;
    koff[p] = krow * 128 + ((kchp ^ (krow & 15)) << 3);   // un-swizzle source chunk
    const int dd = idk >> 2, vch = idk & 3;
    voff[p] = dd * 3072 + (vch << 3);
  }
  const uint16_t* kbh = kb + (size_t)bh * 3072 * 128;
  const uint16_t* vbh = vt + (size_t)bh * 128 * 3072;

  // Q fragments (A-operand): m=l15, k=kc*32+q4*8+j
  bf16x8 qf[4];
  const uint16_t* qrow = qb + ((size_t)bh * 2048 + s_w + l15) * 128;
  #pragma unroll
  for (int kc = 0; kc < 4; ++kc)
    qf[kc] = *(const bf16x8*)&qrow[kc * 32 + q4 * 8];

  f32x4 o[8];
  #pragma unroll
  for (int nt = 0; nt < 8; ++nt) o[nt] = (f32x4){0.f, 0.f, 0.f, 0.f};
  float mrow[4], lrow[4];
  #pragma unroll
  for (int r = 0; r < 4; ++r) { mrow[r] = -1e38f; lrow[r] = 0.f; }

  const float SC = 0.08838834764831845f * 1.4426950408889634f;
  const int ntiles = (q0 + 1088) >> 5;
  const int limw = 1024 + s_w + 15;                 // wave's largest allowed key

  for (int tt = 0; tt < ntiles; ++tt) {
    const int t0 = tt << 5;
    __syncthreads();
    #pragma unroll
    for (int p = 0; p < 2; ++p) {
      gl_lds16(kbh + (size_t)t0 * 128 + koff[p], &lsK[(p * 256 + w * 64) * 8]);
      gl_lds16(vbh + t0 + voff[p],               &lsV[(p * 256 + w * 64) * 8]);
    }
    __syncthreads();
    if (t0 > limw) continue;                        // fully masked for this wave

    f32x4 s0 = (f32x4){0.f,0.f,0.f,0.f}, s1 = (f32x4){0.f,0.f,0.f,0.f};
    #pragma unroll
    for (int kc = 0; kc < 4; ++kc) {
      const int chp = ((kc * 4 + q4) ^ l15) << 3;
      bf16x8 kf0 = *(const bf16x8*)&lsK[l15 * 128 + chp];
      bf16x8 kf1 = *(const bf16x8*)&lsK[(16 + l15) * 128 + chp];
      s0 = MFMA16(qf[kc], kf0, s0);
      s1 = MFMA16(qf[kc], kf1, s1);
    }
    if (t0 + 31 > 1024 + s_w) {                     // diagonal tile: mask (uniform branch)
      #pragma unroll
      for (int r = 0; r < 4; ++r) {
        const int lim = 1024 + s_w + q4 * 4 + r;
        if (t0 + l15      > lim) s0[r] = -1e38f;
        if (t0 + 16 + l15 > lim) s1[r] = -1e38f;
      }
    }
    float alpha[4];
    #pragma unroll
    for (int r = 0; r < 4; ++r) {
      float v = fmaxf(s0[r], s1[r]);
      v = fmaxf(v, __shfl_xor(v, 1)); v = fmaxf(v, __shfl_xor(v, 2));
      v = fmaxf(v, __shfl_xor(v, 4)); v = fmaxf(v, __shfl_xor(v, 8));
      const float mn = fmaxf(mrow[r], v);
      alpha[r] = exp2f((mrow[r] - mn) * SC);
      mrow[r] = mn;
    }
    #pragma unroll
    for (int r = 0; r < 4; ++r) {
      const float nm = -mrow[r] * SC;
      const float p0 = exp2f(fmaf(s0[r], SC, nm));
      const float p1 = exp2f(fmaf(s1[r], SC, nm));
      float ps = p0 + p1;
      ps += __shfl_xor(ps, 1); ps += __shfl_xor(ps, 2);
      ps += __shfl_xor(ps, 4); ps += __shfl_xor(ps, 8);
      lrow[r] = fmaf(lrow[r], alpha[r], ps);
      lsP[w][(q4 * 4 + r) * 40 + l15]      = f2b(p0);
      lsP[w][(q4 * 4 + r) * 40 + 16 + l15] = f2b(p1);
    }
    #pragma unroll
    for (int nt = 0; nt < 8; ++nt)
      #pragma unroll
      for (int r = 0; r < 4; ++r) o[nt][r] *= alpha[r];
    bf16x8 pf = *(const bf16x8*)&lsP[w][l15 * 40 + q4 * 8];
    #pragma unroll
    for (int nt = 0; nt < 8; ++nt) {
      bf16x8 vf = *(const bf16x8*)&lsV[(nt * 16 + l15) * 32 + q4 * 8];
      o[nt] = MFMA16(pf, vf, o[nt]);
    }
  }
  const int b = bh >> 4, h = bh & 15;
  #pragma unroll
  for (int r = 0; r < 4; ++r) {
    const float inv = 1.0f / lrow[r];
    const int s = s_w + q4 * 4 + r;
    uint16_t* orow = ob + ((size_t)b * 2048 + s) * 2048 + h * 128;
    #pragma unroll
    for (int nt = 0; nt < 8; ++nt)
      orow[nt * 16 + l15] = f2b(o[nt][r] * inv);
  }
}

// ---------- GEMM m97-style: async staging, 128x128 tile, BK=32 ----------
template <int EPI>
__global__ __launch_bounds__(256)
void gemm_k(const uint16_t* __restrict__ A, const uint16_t* __restrict__ Bt,
            const float* __restrict__ bias, const float* __restrict__ resid,
            const uint16_t* __restrict__ gbuf, void* __restrict__ outp,
            int M, int N, int K) {
  __shared__ __align__(16) uint16_t lsA[128 * 32];
  __shared__ __align__(16) uint16_t lsB[128 * 32];
  const int tid = threadIdx.x;
  const int lane = tid & 63, wvi = tid >> 6;
  const int l15 = lane & 15, q4 = lane >> 4;
  const int wm = wvi & 1, wn = wvi >> 1;
  const int m0 = blockIdx.y * 128, n0 = blockIdx.x * 128;
  const int lr = lane >> 2, lc = (lane & 3) << 3;

  f32x4 acc[4][4];
  #pragma unroll
  for (int i = 0; i < 4; ++i)
    #pragma unroll
    for (int j = 0; j < 4; ++j) acc[i][j] = (f32x4){0.f, 0.f, 0.f, 0.f};

  const uint16_t* Ab = A + (size_t)m0 * K;
  const uint16_t* Bb = Bt + (size_t)n0 * K;
  for (int k0 = 0; k0 < K; k0 += 32) {
    __syncthreads();
    #pragma unroll
    for (int p = 0; p < 2; ++p) {
      const int row = p * 64 + wvi * 16 + lr;
      gl_lds16(Ab + (size_t)row * K + k0 + lc, &lsA[(p * 256 + wvi * 64) * 8]);
      gl_lds16(Bb + (size_t)row * K + k0 + lc, &lsB[(p * 256 + wvi * 64) * 8]);
    }
    __syncthreads();
    bf16x8 af[4], bfr[4];
    #pragma unroll
    for (int i = 0; i < 4; ++i)
      af[i] = *(const bf16x8*)&lsA[(wm * 64 + i * 16 + l15) * 32 + q4 * 8];
    #pragma unroll
    for (int j = 0; j < 4; ++j)
      bfr[j] = *(const bf16x8*)&lsB[(wn * 64 + j * 16 + l15) * 32 + q4 * 8];
    #pragma unroll
    for (int i = 0; i < 4; ++i)
      #pragma unroll
      for (int j = 0; j < 4; ++j)
        acc[i][j] = MFMA16(af[i], bfr[j], acc[i][j]);
  }
  #pragma unroll
  for (int i = 0; i < 4; ++i) {
    #pragma unroll
    for (int j = 0; j < 4; ++j) {
      const int n = n0 + wn * 64 + j * 16 + l15;
      const float bn = bias[n];
      #pragma unroll
      for (int r = 0; r < 4; ++r) {
        const int m = m0 + wm * 64 + i * 16 + q4 * 4 + r;
        const size_t off = (size_t)m * N + n;
        const float v = acc[i][j][r] + bn;
        if (EPI == 0) {
          ((uint16_t*)outp)[off] = f2b(v);
        } else if (EPI == 1) {
          ((float*)outp)[off] = v + resid[off];
        } else {
          const float g = b2f(gbuf[off]);
          const float sg = g / (1.0f + __expf(-g));
          ((uint16_t*)outp)[off] = f2b(sg * v);
        }
      }
    }
  }
}

// ---------- launch ----------
extern "C" void kernel_launch(void* const* d_in, const int* in_sizes, int n_in,
                              void* d_out, int out_size, void* d_ws, size_t ws_size,
                              hipStream_t stream) {
  const float* x   = (const float*)d_in[0];
  const float* kc  = (const float*)d_in[1];
  const float* vc  = (const float*)d_in[2];
  const float* anw = (const float*)d_in[3];
  const float* fnw = (const float*)d_in[4];
  const float* wq  = (const float*)d_in[5];
  const float* bq  = (const float*)d_in[6];
  const float* wk  = (const float*)d_in[7];
  const float* bk  = (const float*)d_in[8];
  const float* wv_ = (const float*)d_in[9];
  const float* bv  = (const float*)d_in[10];
  const float* wo  = (const float*)d_in[11];
  const float* bo  = (const float*)d_in[12];
  const float* wg  = (const float*)d_in[13];
  const float* bg  = (const float*)d_in[14];
  const float* wva = (const float*)d_in[15];
  const float* bva = (const float*)d_in[16];
  const float* wp  = (const float*)d_in[17];
  const float* bp  = (const float*)d_in[18];
  const float* fc  = (const float*)d_in[19];
  const float* fs  = (const float*)d_in[20];

  float* out_x = (float*)d_out;               // (2,2048,2048)
  float* kat = out_x + 8388608;               // (2,16,3072,128)
  float* vat = kat + 12582912;

  char* ws = (char*)d_ws;
  uint16_t* h_b   = (uint16_t*)(ws);                       // [0,16M)   h bf16
  uint16_t* wbuf  = (uint16_t*)(ws + 16777216);            // [16M,48M) transposed weights
  uint16_t* qkv_b = (uint16_t*)(ws + 50331648);            // [48M,96M) qkv bf16
  uint16_t* k_b   = (uint16_t*)(ws + 50331648);            // overlay after rope: K bf16 natural
  uint16_t* v_t   = (uint16_t*)(ws + 75497472);            // overlay: V bf16 transposed
  uint16_t* q_b   = (uint16_t*)(ws + 100663296);           // [96M,112M) roped Q
  uint16_t* o_b   = (uint16_t*)(ws + 117440512);           // [112M,128M) attn out
  float*    x1    = (float*)   (ws + 134217728);           // [128M,160M) post-attn residual
  float*    bcat  = (float*)   (ws + 167772160);           // 24 KB
  uint16_t* g_b   = qkv_b;                                 // FFN overlay [48M,112M)

  // attention block
  rmsnorm_k<<<4096, 256, 0, stream>>>(x, anw, h_b);
  biascat_k<<<24, 256, 0, stream>>>(bq, bk, bv, bcat);
  transpose_k<<<dim3(64, 64), 256, 0, stream>>>(wq,  wbuf,               2048, 2048);
  transpose_k<<<dim3(64, 64), 256, 0, stream>>>(wk,  wbuf + 1*2048*2048, 2048, 2048);
  transpose_k<<<dim3(64, 64), 256, 0, stream>>>(wv_, wbuf + 2*2048*2048, 2048, 2048);
  gemm_k<0><<<dim3(48, 32), 256, 0, stream>>>(h_b, wbuf, bcat, nullptr, nullptr,
                                              (void*)qkv_b, 4096, 6144, 2048);
  copy_cache_k<<<4096, 256, 0, stream>>>((const float4*)kc, (float4*)kat);
  copy_cache_k<<<4096, 256, 0, stream>>>((const float4*)vc, (float4*)vat);
  rope_k<<<16384, 256, 0, stream>>>(qkv_b, fc, fs, q_b, kat, vat);
  cvt_bf16_k<<<6144, 256, 0, stream>>>(kat, k_b);                 // K -> bf16 natural
  transpose_v_k<<<dim3(96, 4, 32), 256, 0, stream>>>(vat, v_t);   // V -> bf16 [d][t]
  attn_k<<<1024, 256, 0, stream>>>(q_b, k_b, v_t, o_b);
  transpose_k<<<dim3(64, 64), 256, 0, stream>>>(wo, wbuf, 2048, 2048);
  gemm_k<1><<<dim3(16, 32), 256, 0, stream>>>(o_b, wbuf, bo, x, nullptr,
                                              (void*)x1, 4096, 2048, 2048);
  // FFN block
  rmsnorm_k<<<4096, 256, 0, stream>>>(x1, fnw, h_b);
  transpose_k<<<dim3(256, 64), 256, 0, stream>>>(wg, wbuf, 2048, 8192);
  gemm_k<0><<<dim3(64, 32), 256, 0, stream>>>(h_b, wbuf, bg, nullptr, nullptr,
                                              (void*)g_b, 4096, 8192, 2048);
  transpose_k<<<dim3(256, 64), 256, 0, stream>>>(wva, wbuf, 2048, 8192);
  gemm_k<2><<<dim3(64, 32), 256, 0, stream>>>(h_b, wbuf, bva, nullptr, g_b,
                                              (void*)g_b, 4096, 8192, 2048);
  transpose_k<<<dim3(64, 256), 256, 0, stream>>>(wp, wbuf, 8192, 2048);
  gemm_k<1><<<dim3(16, 32), 256, 0, stream>>>(g_b, wbuf, bp, x1, nullptr,
                                              (void*)out_x, 4096, 2048, 8192);
}